// Round 1
// baseline (208.615 us; speedup 1.0000x reference)
//
#include <hip/hip_runtime.h>
#include <math.h>

constexpr int N_NODES = 2000;
constexpr int F_IN    = 512;
constexpr int H_DIM   = 64;

// ---------------------------------------------------------------- degree/count
__global__ __launch_bounds__(256) void deg_count_kernel(
    const int* __restrict__ ei, const float* __restrict__ w,
    float* __restrict__ deg, int* __restrict__ cnt, int E)
{
  int e = blockIdx.x * 256 + threadIdx.x;
  if (e >= E) return;
  int s = ei[e], d = ei[E + e];
  float aw = fabsf(0.5f * w[e]);
  atomicAdd(&deg[d], aw);
  atomicAdd(&deg[s], aw);
  atomicAdd(&cnt[d], 1);
  atomicAdd(&cnt[s], 1);
}

__global__ __launch_bounds__(256) void dinv_kernel(
    const float* __restrict__ deg, float* __restrict__ dinv, int n)
{
  int v = blockIdx.x * 256 + threadIdx.x;
  if (v >= n) return;
  float dg = deg[v];
  dinv[v] = (dg > 0.f) ? (1.f / sqrtf(dg)) : 0.f;
}

// ------------------------------------------------- exclusive scan (n <= 2048)
__global__ __launch_bounds__(1024) void scan_kernel(
    const int* __restrict__ cnt, int* __restrict__ offs, int* __restrict__ fillpos, int n)
{
  __shared__ int bufA[2048], bufB[2048];
  int t = threadIdx.x;
  bufA[t]        = (t < n) ? cnt[t] : 0;
  bufA[t + 1024] = (t + 1024 < n) ? cnt[t + 1024] : 0;
  __syncthreads();
  int* src = bufA; int* dst = bufB;
  for (int d = 1; d < 2048; d <<= 1) {
    #pragma unroll
    for (int k = 0; k < 2; k++) {
      int i = t + k * 1024;
      int v = src[i];
      if (i >= d) v += src[i - d];
      dst[i] = v;
    }
    __syncthreads();
    int* tmp = src; src = dst; dst = tmp;
  }
  for (int k = 0; k < 2; k++) {
    int i = t + k * 1024;
    if (i < n) {
      int ex = (i == 0) ? 0 : src[i - 1];
      offs[i]    = ex;
      fillpos[i] = ex;
    }
  }
  if (t == 0) offs[n] = src[n - 1];
}

// ------------------------------------------------------------------ CSR build
// Per original edge (s,d,w): coeff cr = -norm*cos(th), ci = -norm*sin(th),
// norm = 0.5*w*dinv[s]*dinv[d], th = (pi/2)*w.  Into dst list: (s, cr, +ci);
// into src list: (d, cr, -ci)  [theta negates for the reverse direction].
__global__ __launch_bounds__(256) void build_csr_kernel(
    const int* __restrict__ ei, const float* __restrict__ w,
    const float* __restrict__ dinv, int* __restrict__ fillpos,
    int* __restrict__ nbr, float* __restrict__ cra, float* __restrict__ cia, int E)
{
  int e = blockIdx.x * 256 + threadIdx.x;
  if (e >= E) return;
  int s = ei[e], d = ei[E + e];
  float ww   = w[e];
  float norm = 0.5f * ww * dinv[s] * dinv[d];
  float th   = 1.5707963267948966f * ww;
  float sn, cs;
  sincosf(th, &sn, &cs);
  float cr = -norm * cs;
  float ci = -norm * sn;
  int p1 = atomicAdd(&fillpos[d], 1);
  nbr[p1] = s; cra[p1] = cr; cia[p1] = ci;
  int p2 = atomicAdd(&fillpos[s], 1);
  nbr[p2] = d; cra[p2] = cr; cia[p2] = -ci;
}

// ----------------------------------------------------------------------- GEMM
// C[M x 64] = A[M x K] @ W[K x 64], which = blockIdx.y selects
// {A in (real,imag)} x {W half 0/1} -> P0r/P0i/P1r/P1i. grid.z = K-split.
__global__ __launch_bounds__(256) void gemm_kernel(
    const float* __restrict__ Ar, const float* __restrict__ Ai,
    const float* __restrict__ Wb,
    float* __restrict__ P0r, float* __restrict__ P0i,
    float* __restrict__ P1r, float* __restrict__ P1i,
    int M, int K, int accumulate)
{
  __shared__ float As[64][65];   // +1 pad: breaks stride-64 bank conflict
  __shared__ float Ws[64][64];
  int t = threadIdx.x;
  int which = blockIdx.y;
  const float* A = (which & 1) ? Ai : Ar;
  const float* W = Wb + (size_t)(which >> 1) * K * H_DIM;
  float* C = (which == 0) ? P0r : (which == 1) ? P0i : (which == 2) ? P1r : P1i;
  int r0 = blockIdx.x * 64;
  int kchunk = K / gridDim.z;
  int kbeg = blockIdx.z * kchunk;
  int kend = kbeg + kchunk;
  int tx = t & 15, ty = t >> 4;
  float acc[4][4] = {};
  for (int k0 = kbeg; k0 < kend; k0 += 64) {
    #pragma unroll
    for (int i = 0; i < 16; i++) {
      int idx = t + i * 256;
      int row = idx >> 6, kk = idx & 63;
      int gr = r0 + row;
      As[row][kk] = (gr < M) ? A[(size_t)gr * K + k0 + kk] : 0.f;
    }
    #pragma unroll
    for (int i = 0; i < 16; i++) {
      int idx = t + i * 256;
      int kk = idx >> 6, col = idx & 63;
      Ws[kk][col] = W[(size_t)(k0 + kk) * H_DIM + col];
    }
    __syncthreads();
    #pragma unroll
    for (int kk = 0; kk < 64; kk++) {
      float4 wv = *reinterpret_cast<const float4*>(&Ws[kk][tx * 4]);
      float av[4];
      #pragma unroll
      for (int r = 0; r < 4; r++) av[r] = As[ty * 4 + r][kk];
      #pragma unroll
      for (int r = 0; r < 4; r++) {
        acc[r][0] = fmaf(av[r], wv.x, acc[r][0]);
        acc[r][1] = fmaf(av[r], wv.y, acc[r][1]);
        acc[r][2] = fmaf(av[r], wv.z, acc[r][2]);
        acc[r][3] = fmaf(av[r], wv.w, acc[r][3]);
      }
    }
    __syncthreads();
  }
  #pragma unroll
  for (int r = 0; r < 4; r++) {
    int gr = r0 + ty * 4 + r;
    if (gr >= M) continue;
    size_t o = (size_t)gr * H_DIM + tx * 4;
    if (accumulate) {
      atomicAdd(&C[o + 0], acc[r][0]);
      atomicAdd(&C[o + 1], acc[r][1]);
      atomicAdd(&C[o + 2], acc[r][2]);
      atomicAdd(&C[o + 3], acc[r][3]);
    } else {
      *reinterpret_cast<float4*>(&C[o]) =
          make_float4(acc[r][0], acc[r][1], acc[r][2], acc[r][3]);
    }
  }
}

// ------------------------------------------------------- aggregate + add + ReLU
// out_r = P0r[v] + sum_j cr*P1r[u] - ci*P1i[u]; out_i analog; mask by out_r>=0.
__global__ __launch_bounds__(256) void aggregate_kernel(
    const int* __restrict__ offs, const int* __restrict__ nbr,
    const float* __restrict__ cra, const float* __restrict__ cia,
    const float* __restrict__ P0r, const float* __restrict__ P0i,
    const float* __restrict__ P1r, const float* __restrict__ P1i,
    float* __restrict__ xr, float* __restrict__ xi, int n)
{
  int v = blockIdx.x * 4 + (threadIdx.x >> 6);
  int h = threadIdx.x & 63;
  if (v >= n) return;
  int beg = offs[v], end = offs[v + 1];
  float ar = P0r[v * H_DIM + h];
  float ai = P0i[v * H_DIM + h];
  for (int j = beg; j < end; j++) {
    int u   = nbr[j];
    float cr = cra[j], ci = cia[j];
    float pr = P1r[u * H_DIM + h];
    float pi = P1i[u * H_DIM + h];
    ar = fmaf(cr, pr, ar); ar = fmaf(-ci, pi, ar);
    ai = fmaf(cr, pi, ai); ai = fmaf( ci, pr, ai);
  }
  if (ar < 0.f) { ar = 0.f; ai = 0.f; }
  xr[v * H_DIM + h] = ar;
  xi[v * H_DIM + h] = ai;
}

// -------------------------------------------------------------- query head
// wave-per-query, lane = feature dim; x = [r_ni, r_nj, i_ni, i_nj, sim] (320)
__global__ __launch_bounds__(256) void query_kernel(
    const int* __restrict__ qe,
    const float* __restrict__ xr, const float* __restrict__ xi,
    const float* __restrict__ emb,
    const float* __restrict__ lw, const float* __restrict__ lb,
    float* __restrict__ out, int Qn, int n)
{
  int wid = (blockIdx.x * 256 + threadIdx.x) >> 6;
  int h   = threadIdx.x & 63;
  if (wid >= Qn) return;
  int ni = qe[2 * wid], nj = qe[2 * wid + 1];
  const float2* lw2 = reinterpret_cast<const float2*>(lw);
  float a = xr[ni * H_DIM + h];
  float b = xr[nj * H_DIM + h];
  float c = xi[ni * H_DIM + h];
  float d = xi[nj * H_DIM + h];
  float s = emb[(size_t)(ni * n + nj) * H_DIM + h];
  float2 w0 = lw2[h];
  float2 w1 = lw2[64 + h];
  float2 w2 = lw2[128 + h];
  float2 w3 = lw2[192 + h];
  float2 w4 = lw2[256 + h];
  float acc0 = a * w0.x + b * w1.x + c * w2.x + d * w3.x + s * w4.x;
  float acc1 = a * w0.y + b * w1.y + c * w2.y + d * w3.y + s * w4.y;
  #pragma unroll
  for (int off = 1; off < 64; off <<= 1) {
    acc0 += __shfl_xor(acc0, off, 64);
    acc1 += __shfl_xor(acc1, off, 64);
  }
  if (h == 0) {
    float l0 = acc0 + lb[0], l1 = acc1 + lb[1];
    float m  = fmaxf(l0, l1);
    float lse = m + logf(expf(l0 - m) + expf(l1 - m));
    reinterpret_cast<float2*>(out)[wid] = make_float2(l0 - lse, l1 - lse);
  }
}

// ------------------------------------------------------------------- launcher
extern "C" void kernel_launch(void* const* d_in, const int* in_sizes, int n_in,
                              void* d_out, int out_size, void* d_ws, size_t ws_size,
                              hipStream_t stream)
{
  const float* real = (const float*)d_in[0];
  const float* imag = (const float*)d_in[1];
  const int*   ei   = (const int*)d_in[2];
  const int*   qe   = (const int*)d_in[3];
  const float* emb  = (const float*)d_in[4];
  const float* ew   = (const float*)d_in[5];
  const float* W1   = (const float*)d_in[6];
  const float* W2   = (const float*)d_in[7];
  const float* lw   = (const float*)d_in[8];
  const float* lb   = (const float*)d_in[9];
  float* out = (float*)d_out;

  int E = in_sizes[2] / 2;
  int Q = in_sizes[3] / 2;
  int n = N_NODES;

  char* ws = (char*)d_ws;
  size_t off = 0;
  auto alloc = [&](size_t bytes) -> char* {
    char* p = ws + off;
    off = (off + bytes + 255) & ~(size_t)255;
    return p;
  };
  float* deg   = (float*)alloc(2048 * 4);
  int*   cnt   = (int*)  alloc(2048 * 4);
  float* dinv  = (float*)alloc(2048 * 4);
  int*   offs  = (int*)  alloc((2048 + 1) * 4);
  int*   fillp = (int*)  alloc(2048 * 4);
  int*   nbr   = (int*)  alloc((size_t)2 * E * 4);
  float* cra   = (float*)alloc((size_t)2 * E * 4);
  float* cia   = (float*)alloc((size_t)2 * E * 4);
  float* P0r   = (float*)alloc((size_t)n * H_DIM * 4);
  float* P0i   = (float*)alloc((size_t)n * H_DIM * 4);
  float* P1r   = (float*)alloc((size_t)n * H_DIM * 4);
  float* P1i   = (float*)alloc((size_t)n * H_DIM * 4);
  float* xr1   = (float*)alloc((size_t)n * H_DIM * 4);
  float* xi1   = (float*)alloc((size_t)n * H_DIM * 4);
  float* xr2   = (float*)alloc((size_t)n * H_DIM * 4);
  float* xi2   = (float*)alloc((size_t)n * H_DIM * 4);

  // deg & cnt are contiguous 8 KiB blocks -> single 16 KiB clear
  hipMemsetAsync(deg, 0, 2 * 2048 * 4, stream);

  int eb = (E + 255) / 256;
  deg_count_kernel<<<eb, 256, 0, stream>>>(ei, ew, deg, cnt, E);
  dinv_kernel<<<(n + 255) / 256, 256, 0, stream>>>(deg, dinv, n);
  scan_kernel<<<1, 1024, 0, stream>>>(cnt, offs, fillp, n);
  build_csr_kernel<<<eb, 256, 0, stream>>>(ei, ew, dinv, fillp, nbr, cra, cia, E);

  // P0r..P1i contiguous (each 512000 B, 256-aligned) -> single clear
  hipMemsetAsync(P0r, 0, (size_t)4 * n * H_DIM * 4, stream);

  dim3 g1((n + 63) / 64, 4, 2);   // K-split=2, atomic accumulate
  gemm_kernel<<<g1, 256, 0, stream>>>(real, imag, W1, P0r, P0i, P1r, P1i, n, F_IN, 1);
  aggregate_kernel<<<(n + 3) / 4, 256, 0, stream>>>(offs, nbr, cra, cia,
                                                    P0r, P0i, P1r, P1i, xr1, xi1, n);
  dim3 g2((n + 63) / 64, 4, 1);
  gemm_kernel<<<g2, 256, 0, stream>>>(xr1, xi1, W2, P0r, P0i, P1r, P1i, n, H_DIM, 0);
  aggregate_kernel<<<(n + 3) / 4, 256, 0, stream>>>(offs, nbr, cra, cia,
                                                    P0r, P0i, P1r, P1i, xr2, xi2, n);

  query_kernel<<<(Q + 3) / 4, 256, 0, stream>>>(qe, xr2, xi2, emb, lw, lb, out, Q, n);
}

// Round 2
// 140.466 us; speedup vs baseline: 1.4852x; 1.4852x over previous
//
#include <hip/hip_runtime.h>
#include <math.h>

constexpr int N_NODES = 2000;
constexpr int F_IN    = 512;
constexpr int H_DIM   = 64;
constexpr int SLOT_SH = 8;     // 256 slots per node in slot-CSR

// ---------------------------------------------------------------- degree
__global__ __launch_bounds__(256) void deg_kernel(
    const int* __restrict__ ei, const float* __restrict__ w,
    float* __restrict__ deg, int E)
{
  int e = blockIdx.x * 256 + threadIdx.x;
  if (e >= E) return;
  int s = ei[e], d = ei[E + e];
  float aw = fabsf(0.5f * w[e]);
  atomicAdd(&deg[d], aw);
  atomicAdd(&deg[s], aw);
}

// ------------------------------------------------------------- slot-CSR build
// Per edge (s,d,w): norm = 0.5*w*dinv[s]*dinv[d], th=(pi/2)*w,
// cr=-norm*cos(th), ci=-norm*sin(th).
// Into d's list: (s, cr, +ci); into s's list: (d, cr, -ci).
__global__ __launch_bounds__(256) void build_slots_kernel(
    const int* __restrict__ ei, const float* __restrict__ w,
    const float* __restrict__ deg, int* __restrict__ cnt,
    int* __restrict__ nbr, float* __restrict__ cra, float* __restrict__ cia, int E)
{
  int e = blockIdx.x * 256 + threadIdx.x;
  if (e >= E) return;
  int s = ei[e], d = ei[E + e];
  float ww = w[e];
  float degs = deg[s], degd = deg[d];
  float dvs = (degs > 0.f) ? rsqrtf(degs) : 0.f;
  float dvd = (degd > 0.f) ? rsqrtf(degd) : 0.f;
  float norm = 0.5f * ww * dvs * dvd;
  float sn, cs;
  sincosf(1.5707963267948966f * ww, &sn, &cs);
  float cr = -norm * cs;
  float ci = -norm * sn;
  int p1 = atomicAdd(&cnt[d], 1);
  int i1 = (d << SLOT_SH) + p1;
  nbr[i1] = s; cra[i1] = cr; cia[i1] = ci;
  int p2 = atomicAdd(&cnt[s], 1);
  int i2 = (s << SLOT_SH) + p2;
  nbr[i2] = d; cra[i2] = cr; cia[i2] = -ci;
}

// ----------------------------------------------------------------------- GEMM
// C[M x 64] = A[M x K] @ W[K x 64]; blockIdx.y selects
// {A in (real,imag)} x {W half 0/1} -> P0r/P0i/P1r/P1i. grid.z = K-split.
__global__ __launch_bounds__(256) void gemm_kernel(
    const float* __restrict__ Ar, const float* __restrict__ Ai,
    const float* __restrict__ Wb,
    float* __restrict__ P0r, float* __restrict__ P0i,
    float* __restrict__ P1r, float* __restrict__ P1i,
    int M, int K, int accumulate)
{
  __shared__ float As[64][65];   // +1 pad: breaks stride-64 bank conflict
  __shared__ float Ws[64][64];
  int t = threadIdx.x;
  int which = blockIdx.y;
  const float* A = (which & 1) ? Ai : Ar;
  const float* W = Wb + (size_t)(which >> 1) * K * H_DIM;
  float* C = (which == 0) ? P0r : (which == 1) ? P0i : (which == 2) ? P1r : P1i;
  int r0 = blockIdx.x * 64;
  int kchunk = K / gridDim.z;
  int kbeg = blockIdx.z * kchunk;
  int kend = kbeg + kchunk;
  int tx = t & 15, ty = t >> 4;
  float acc[4][4] = {};
  for (int k0 = kbeg; k0 < kend; k0 += 64) {
    #pragma unroll
    for (int i = 0; i < 16; i++) {
      int idx = t + i * 256;
      int row = idx >> 6, kk = idx & 63;
      int gr = r0 + row;
      As[row][kk] = (gr < M) ? A[(size_t)gr * K + k0 + kk] : 0.f;
    }
    #pragma unroll
    for (int i = 0; i < 16; i++) {
      int idx = t + i * 256;
      int kk = idx >> 6, col = idx & 63;
      Ws[kk][col] = W[(size_t)(k0 + kk) * H_DIM + col];
    }
    __syncthreads();
    #pragma unroll
    for (int kk = 0; kk < 64; kk++) {
      float4 wv = *reinterpret_cast<const float4*>(&Ws[kk][tx * 4]);
      float av[4];
      #pragma unroll
      for (int r = 0; r < 4; r++) av[r] = As[ty * 4 + r][kk];
      #pragma unroll
      for (int r = 0; r < 4; r++) {
        acc[r][0] = fmaf(av[r], wv.x, acc[r][0]);
        acc[r][1] = fmaf(av[r], wv.y, acc[r][1]);
        acc[r][2] = fmaf(av[r], wv.z, acc[r][2]);
        acc[r][3] = fmaf(av[r], wv.w, acc[r][3]);
      }
    }
    __syncthreads();
  }
  #pragma unroll
  for (int r = 0; r < 4; r++) {
    int gr = r0 + ty * 4 + r;
    if (gr >= M) continue;
    size_t o = (size_t)gr * H_DIM + tx * 4;
    if (accumulate) {
      atomicAdd(&C[o + 0], acc[r][0]);
      atomicAdd(&C[o + 1], acc[r][1]);
      atomicAdd(&C[o + 2], acc[r][2]);
      atomicAdd(&C[o + 3], acc[r][3]);
    } else {
      *reinterpret_cast<float4*>(&C[o]) =
          make_float4(acc[r][0], acc[r][1], acc[r][2], acc[r][3]);
    }
  }
}

// --------------------------------------------- layer-1 aggregate + add + ReLU
// block per node, 4 waves split the neighbor list, LDS combine.
__global__ __launch_bounds__(256) void aggregate1_kernel(
    const int* __restrict__ cnt, const int* __restrict__ nbr,
    const float* __restrict__ cra, const float* __restrict__ cia,
    const float* __restrict__ P0r, const float* __restrict__ P0i,
    const float* __restrict__ P1r, const float* __restrict__ P1i,
    float* __restrict__ xr, float* __restrict__ xi)
{
  __shared__ float sr[4][64], si[4][64];
  int v = blockIdx.x;
  int h = threadIdx.x & 63;
  int wv = threadIdx.x >> 6;
  int cv = cnt[v];
  float ar = 0.f, ai = 0.f;
  for (int j = wv; j < cv; j += 4) {
    int idx = (v << SLOT_SH) + j;
    int u = nbr[idx];
    float cr = cra[idx], ci = cia[idx];
    float pr = P1r[u * H_DIM + h];
    float pi = P1i[u * H_DIM + h];
    ar = fmaf(cr, pr, ar); ar = fmaf(-ci, pi, ar);
    ai = fmaf(cr, pi, ai); ai = fmaf( ci, pr, ai);
  }
  sr[wv][h] = ar; si[wv][h] = ai;
  __syncthreads();
  if (wv == 0) {
    ar = sr[0][h] + sr[1][h] + sr[2][h] + sr[3][h] + P0r[v * H_DIM + h];
    ai = si[0][h] + si[1][h] + si[2][h] + si[3][h] + P0i[v * H_DIM + h];
    if (ar < 0.f) { ar = 0.f; ai = 0.f; }
    xr[v * H_DIM + h] = ar;
    xi[v * H_DIM + h] = ai;
  }
}

// -------------------- layer-2 aggregate + ReLU + per-node partial logits
// u[v][c] = sum_h r[h]*lw[h][c]     + i[h]*lw[128+h][c]   (+ lb[c])
// w[v][c] = sum_h r[h]*lw[64+h][c]  + i[h]*lw[192+h][c]
__global__ __launch_bounds__(256) void aggregate2_kernel(
    const int* __restrict__ cnt, const int* __restrict__ nbr,
    const float* __restrict__ cra, const float* __restrict__ cia,
    const float* __restrict__ P0r, const float* __restrict__ P0i,
    const float* __restrict__ P1r, const float* __restrict__ P1i,
    const float* __restrict__ lw, const float* __restrict__ lb,
    float4* __restrict__ node_uw)
{
  __shared__ float sr[4][64], si[4][64];
  int v = blockIdx.x;
  int h = threadIdx.x & 63;
  int wv = threadIdx.x >> 6;
  int cv = cnt[v];
  float ar = 0.f, ai = 0.f;
  for (int j = wv; j < cv; j += 4) {
    int idx = (v << SLOT_SH) + j;
    int u = nbr[idx];
    float cr = cra[idx], ci = cia[idx];
    float pr = P1r[u * H_DIM + h];
    float pi = P1i[u * H_DIM + h];
    ar = fmaf(cr, pr, ar); ar = fmaf(-ci, pi, ar);
    ai = fmaf(cr, pi, ai); ai = fmaf( ci, pr, ai);
  }
  sr[wv][h] = ar; si[wv][h] = ai;
  __syncthreads();
  if (wv == 0) {
    ar = sr[0][h] + sr[1][h] + sr[2][h] + sr[3][h] + P0r[v * H_DIM + h];
    ai = si[0][h] + si[1][h] + si[2][h] + si[3][h] + P0i[v * H_DIM + h];
    if (ar < 0.f) { ar = 0.f; ai = 0.f; }
    const float2* lw2 = reinterpret_cast<const float2*>(lw);
    float2 l0 = lw2[h], l1 = lw2[64 + h], l2 = lw2[128 + h], l3 = lw2[192 + h];
    float u0 = ar * l0.x + ai * l2.x;
    float u1 = ar * l0.y + ai * l2.y;
    float w0 = ar * l1.x + ai * l3.x;
    float w1 = ar * l1.y + ai * l3.y;
    #pragma unroll
    for (int off = 1; off < 64; off <<= 1) {
      u0 += __shfl_xor(u0, off, 64);
      u1 += __shfl_xor(u1, off, 64);
      w0 += __shfl_xor(w0, off, 64);
      w1 += __shfl_xor(w1, off, 64);
    }
    if (h == 0)
      node_uw[v] = make_float4(u0 + lb[0], u1 + lb[1], w0, w1);
  }
}

// -------------------------------------------------------------- query head
// 16 lanes per query; lane l loads float4 of the sim row.
// logit[c] = node_uw[ni].{x,y} + node_uw[nj].{z,w} + sim . lw[256:,c]
__global__ __launch_bounds__(256) void query_kernel(
    const int* __restrict__ qe,
    const float* __restrict__ emb,
    const float* __restrict__ lw,
    const float4* __restrict__ node_uw,
    float* __restrict__ out, int Qn, int n)
{
  int gq = (blockIdx.x * 256 + threadIdx.x) >> 4;
  int l  = threadIdx.x & 15;
  if (gq >= Qn) return;
  int ni = qe[2 * gq], nj = qe[2 * gq + 1];
  const float4* emb4 = reinterpret_cast<const float4*>(emb);
  float4 s4 = emb4[(size_t)(ni * n + nj) * 16 + l];
  const float2* lw2 = reinterpret_cast<const float2*>(lw);
  float2 wa = lw2[256 + 4 * l];
  float2 wb = lw2[257 + 4 * l];
  float2 wc = lw2[258 + 4 * l];
  float2 wd = lw2[259 + 4 * l];
  float acc0 = s4.x * wa.x + s4.y * wb.x + s4.z * wc.x + s4.w * wd.x;
  float acc1 = s4.x * wa.y + s4.y * wb.y + s4.z * wc.y + s4.w * wd.y;
  #pragma unroll
  for (int off = 1; off < 16; off <<= 1) {
    acc0 += __shfl_xor(acc0, off, 64);
    acc1 += __shfl_xor(acc1, off, 64);
  }
  if (l == 0) {
    float4 uni = node_uw[ni];
    float4 unj = node_uw[nj];
    float lg0 = acc0 + uni.x + unj.z;
    float lg1 = acc1 + uni.y + unj.w;
    float m = fmaxf(lg0, lg1);
    float lse = m + logf(expf(lg0 - m) + expf(lg1 - m));
    reinterpret_cast<float2*>(out)[gq] = make_float2(lg0 - lse, lg1 - lse);
  }
}

// ------------------------------------------------------------------- launcher
extern "C" void kernel_launch(void* const* d_in, const int* in_sizes, int n_in,
                              void* d_out, int out_size, void* d_ws, size_t ws_size,
                              hipStream_t stream)
{
  const float* real = (const float*)d_in[0];
  const float* imag = (const float*)d_in[1];
  const int*   ei   = (const int*)d_in[2];
  const int*   qe   = (const int*)d_in[3];
  const float* emb  = (const float*)d_in[4];
  const float* ew   = (const float*)d_in[5];
  const float* W1   = (const float*)d_in[6];
  const float* W2   = (const float*)d_in[7];
  const float* lw   = (const float*)d_in[8];
  const float* lb   = (const float*)d_in[9];
  float* out = (float*)d_out;

  int E = in_sizes[2] / 2;
  int Q = in_sizes[3] / 2;
  int n = N_NODES;
  int nslots = N_NODES << SLOT_SH;   // 512000

  char* ws = (char*)d_ws;
  size_t off = 0;
  auto alloc = [&](size_t bytes) -> char* {
    char* p = ws + off;
    off = (off + bytes + 255) & ~(size_t)255;
    return p;
  };
  // deg, cnt, P0r..P1i contiguous -> ONE memset covers all zero-init state
  float*  deg  = (float*) alloc(2048 * 4);
  int*    cnt  = (int*)   alloc(2048 * 4);
  float*  P0r  = (float*) alloc((size_t)n * H_DIM * 4);
  float*  P0i  = (float*) alloc((size_t)n * H_DIM * 4);
  float*  P1r  = (float*) alloc((size_t)n * H_DIM * 4);
  float*  P1i  = (float*) alloc((size_t)n * H_DIM * 4);
  size_t zero_bytes = (size_t)((char*)(P1i + (size_t)n * H_DIM) - (char*)deg);
  int*    nbr  = (int*)   alloc((size_t)nslots * 4);
  float*  cra  = (float*) alloc((size_t)nslots * 4);
  float*  cia  = (float*) alloc((size_t)nslots * 4);
  float*  xr1  = (float*) alloc((size_t)n * H_DIM * 4);
  float*  xi1  = (float*) alloc((size_t)n * H_DIM * 4);
  float4* nuw  = (float4*)alloc((size_t)n * 16);

  hipMemsetAsync(deg, 0, zero_bytes, stream);

  int eb = (E + 255) / 256;
  deg_kernel<<<eb, 256, 0, stream>>>(ei, ew, deg, E);
  build_slots_kernel<<<eb, 256, 0, stream>>>(ei, ew, deg, cnt, nbr, cra, cia, E);

  dim3 g1((n + 63) / 64, 4, 2);   // K-split=2, atomic accumulate
  gemm_kernel<<<g1, 256, 0, stream>>>(real, imag, W1, P0r, P0i, P1r, P1i, n, F_IN, 1);
  aggregate1_kernel<<<n, 256, 0, stream>>>(cnt, nbr, cra, cia,
                                           P0r, P0i, P1r, P1i, xr1, xi1);
  dim3 g2((n + 63) / 64, 4, 1);
  gemm_kernel<<<g2, 256, 0, stream>>>(xr1, xi1, W2, P0r, P0i, P1r, P1i, n, H_DIM, 0);
  aggregate2_kernel<<<n, 256, 0, stream>>>(cnt, nbr, cra, cia,
                                           P0r, P0i, P1r, P1i, lw, lb, nuw);

  query_kernel<<<(Q * 16 + 255) / 256, 256, 0, stream>>>(qe, emb, lw, nuw, out, Q, n);
}